// Round 1
// baseline (786.805 us; speedup 1.0000x reference)
//
#include <hip/hip_runtime.h>
#include <hip/hip_bf16.h>

typedef __attribute__((ext_vector_type(8))) short short8;
typedef __attribute__((ext_vector_type(4))) float floatx4;

#define D_DIM 256
#define K_DIM 768
#define TILE 128
#define APAD 40  // LDS row stride in shorts: 80B = 20 banks -> max 2-way aliasing (free)

// fp32 -> bf16 round-to-nearest-even (no NaN path needed: Gaussian inputs)
__device__ __forceinline__ short f2bf(float x) {
    union { float f; unsigned u; } a; a.f = x;
    unsigned r = a.u + 0x7fffu + ((a.u >> 16) & 1u);
    return (short)(r >> 16);
}

// W [K_DIM][D_DIM] fp32 -> Wt [D_DIM][K_DIM] bf16 (transpose + convert), 32x32 LDS tiles
__global__ __launch_bounds__(256) void wt_kernel(const float* __restrict__ W,
                                                 short* __restrict__ Wt) {
    __shared__ float tile[32][33];
    const int k0 = blockIdx.x * 32, n0 = blockIdx.y * 32;
    const int tx = threadIdx.x & 31, ty = threadIdx.x >> 5;  // ty 0..7
#pragma unroll
    for (int i = 0; i < 32; i += 8)
        tile[ty + i][tx] = W[(size_t)(k0 + ty + i) * D_DIM + n0 + tx];
    __syncthreads();
#pragma unroll
    for (int i = 0; i < 32; i += 8)
        Wt[(size_t)(n0 + ty + i) * K_DIM + k0 + tx] = f2bf(tile[tx][ty + i]);
}

// Fused gather + GEMM + bias + relu.
// C tile 128x128 per block; 4 waves in 2x2, each wave 64x64 via 4x4 mfma_f32_16x16x32_bf16.
__global__ __launch_bounds__(256, 3) void edge_gemm(
    const float* __restrict__ edge, const float* __restrict__ node,
    const int* __restrict__ src, const int* __restrict__ tgt,
    const short* __restrict__ Wt, const float* __restrict__ bias,
    float* __restrict__ out, int E)
{
    __shared__ short As[TILE][APAD];
    __shared__ short Bs[TILE][APAD];
    __shared__ int sidx[TILE], tidx[TILE];

    const int tid = threadIdx.x;
    const int m0 = blockIdx.y * TILE;
    const int n0 = blockIdx.x * TILE;

    if (tid < TILE) {
        int r = m0 + tid; if (r >= E) r = E - 1;  // clamp tail rows (stores are guarded)
        sidx[tid] = src[r];
        tidx[tid] = tgt[r];
    }
    __syncthreads();

    // --- staging assignment: thread -> (row, half-row of 16 floats) ---
    const int srow = tid >> 1;   // 0..127
    const int half = tid & 1;    // 0,1
    int rs = m0 + srow; if (rs >= E) rs = E - 1;
    const float* ab0 = edge + (size_t)rs * D_DIM + half * 16;
    const float* ab1 = node + (size_t)sidx[srow] * D_DIM + half * 16;
    const float* ab2 = node + (size_t)tidx[srow] * D_DIM + half * 16;
    const short* wb  = Wt + (size_t)(n0 + srow) * K_DIM + half * 16;
    short* aw = &As[srow][half * 16];
    short* bw = &Bs[srow][half * 16];

    // --- MFMA fragment coords ---
    const int lane = tid & 63;
    const int wm = ((tid >> 7) & 1) * 64;  // waves {0,1}->0, {2,3}->64
    const int wn = ((tid >> 6) & 1) * 64;  // waves {0,2}->0, {1,3}->64
    const int fr = lane & 15;              // A row / B col / C col index
    const int kq = (lane >> 4) * 8;        // k-quad offset

    floatx4 acc[4][4] = {};

    const float* abases[3] = { ab0, ab1, ab2 };

#pragma unroll
    for (int seg = 0; seg < 3; ++seg) {
        const float* ab = abases[seg];
        const short* wbs = wb + seg * D_DIM;  // seg*256 along k of Wt row
        for (int it = 0; it < 8; ++it) {
            // issue global loads before the barrier so they fly over prior MFMA drain
            const float4* ap = (const float4*)(ab + it * 32);
            float4 f0 = ap[0], f1 = ap[1], f2 = ap[2], f3 = ap[3];
            const short8* wp = (const short8*)(wbs + it * 32);
            short8 w0 = wp[0], w1 = wp[1];

            __syncthreads();  // prior tiles fully consumed

            union { short8 v; short s[8]; } u0, u1;
            u0.s[0] = f2bf(f0.x); u0.s[1] = f2bf(f0.y); u0.s[2] = f2bf(f0.z); u0.s[3] = f2bf(f0.w);
            u0.s[4] = f2bf(f1.x); u0.s[5] = f2bf(f1.y); u0.s[6] = f2bf(f1.z); u0.s[7] = f2bf(f1.w);
            u1.s[0] = f2bf(f2.x); u1.s[1] = f2bf(f2.y); u1.s[2] = f2bf(f2.z); u1.s[3] = f2bf(f2.w);
            u1.s[4] = f2bf(f3.x); u1.s[5] = f2bf(f3.y); u1.s[6] = f2bf(f3.z); u1.s[7] = f2bf(f3.w);
            *(short8*)aw = u0.v;       *((short8*)aw + 1) = u1.v;
            *(short8*)bw = w0;         *((short8*)bw + 1) = w1;

            __syncthreads();

            short8 afr[4], bfr[4];
#pragma unroll
            for (int i = 0; i < 4; ++i) afr[i] = *(const short8*)&As[wm + i * 16 + fr][kq];
#pragma unroll
            for (int j = 0; j < 4; ++j) bfr[j] = *(const short8*)&Bs[wn + j * 16 + fr][kq];
#pragma unroll
            for (int i = 0; i < 4; ++i)
#pragma unroll
                for (int j = 0; j < 4; ++j)
                    acc[i][j] = __builtin_amdgcn_mfma_f32_16x16x32_bf16(
                        afr[i], bfr[j], acc[i][j], 0, 0, 0);
        }
    }

    // --- epilogue: bias + relu + guarded store ---
    float bv[4];
#pragma unroll
    for (int j = 0; j < 4; ++j) bv[j] = bias[n0 + wn + j * 16 + fr];
    const int rq = (lane >> 4) * 4;
#pragma unroll
    for (int i = 0; i < 4; ++i) {
        const int rbase = m0 + wm + i * 16 + rq;
#pragma unroll
        for (int j = 0; j < 4; ++j) {
            const int c = n0 + wn + j * 16 + fr;
#pragma unroll
            for (int r = 0; r < 4; ++r) {
                const int rr = rbase + r;
                if (rr < E) {
                    float v = acc[i][j][r] + bv[j];
                    out[(size_t)rr * D_DIM + c] = v > 0.f ? v : 0.f;
                }
            }
        }
    }
}

extern "C" void kernel_launch(void* const* d_in, const int* in_sizes, int n_in,
                              void* d_out, int out_size, void* d_ws, size_t ws_size,
                              hipStream_t stream) {
    const float* edge = (const float*)d_in[0];
    const float* node = (const float*)d_in[1];
    const int*   srcI = (const int*)d_in[2];
    const int*   tgtI = (const int*)d_in[3];
    const float* W    = (const float*)d_in[4];
    const float* bias = (const float*)d_in[5];
    float* out = (float*)d_out;
    const int E = in_sizes[2];  // n_edges
    short* Wt = (short*)d_ws;   // needs K_DIM*D_DIM*2 = 393216 bytes

    dim3 tgrid(K_DIM / 32, D_DIM / 32);
    wt_kernel<<<tgrid, dim3(256), 0, stream>>>(W, Wt);

    dim3 ggrid(D_DIM / TILE, (E + TILE - 1) / TILE);  // N-block fastest -> A-tile L2/L3 reuse
    edge_gemm<<<ggrid, dim3(256), 0, stream>>>(edge, node, srcI, tgtI, Wt, bias, out, E);
}